// Round 1
// baseline (1034.397 us; speedup 1.0000x reference)
//
#include <hip/hip_runtime.h>

// Problem constants (from reference setup_inputs)
#define T_STEPS 120
#define BATCH   2048
#define HID     512
#define OUTN    2

// Output layout (flat, return order):
//  spk1_rec (T,B,H)  : 120*2048*512 = 125829120
//  mem1_rec (T,B,H)  : 125829120
//  spk2_rec (T,B,O)  : 491520
//  mem2_rec (T,B,O)  : 491520
//  hidden_spike_count: 1
//  output_spike_count: 1
#define SPK1_OFF 0LL
#define MEM1_OFF 125829120LL
#define SPK2_OFF 251658240LL
#define MEM2_OFF 252149760LL
#define CNT_OFF  252641280LL

typedef float f32x4 __attribute__((ext_vector_type(4)));

__global__ void zero_counts_kernel(float* cnts) {
    cnts[0] = 0.0f;
    cnts[1] = 0.0f;
}

// One block per batch row b. 128 threads; each thread owns 4 consecutive
// hidden neurons (h = tid*4 .. tid*4+3) so spk1/mem1 are written as
// coalesced nontemporal float4 (16 B/lane — the coalescing sweet spot).
//
// Key structural change vs previous version: NO barriers inside the
// t-loop. The output layer's per-t reduction over H is handled by
// pre-zeroing red[t][wave][o] in LDS once; inside the loop, only
// timesteps where a wave actually spikes (ballot-guarded, spikes are
// rare) do the shuffle reduce + LDS write. One __syncthreads() after
// the loop, then threads 0/1 run the serial mem2 recurrence (one output
// neuron each) from the LDS partials.
__global__ __launch_bounds__(128) void snn_fwd_kernel(
    const float* __restrict__ x,       // (B,T)
    const float* __restrict__ W1,      // (H,1)
    const float* __restrict__ W2,      // (O,H), already *H per setup
    const float* __restrict__ beta_h,  // (H)
    const float* __restrict__ thr_h,   // (H)
    const float* __restrict__ beta_o,  // (O)
    const float* __restrict__ thr_o,   // (O)
    float* __restrict__ spk1_rec,
    float* __restrict__ mem1_rec,
    float* __restrict__ spk2_rec,
    float* __restrict__ mem2_rec,
    float* __restrict__ cnts)
{
    const int tid  = threadIdx.x;
    const int b    = blockIdx.x;
    const int wid  = tid >> 6;   // 0..1
    const int lane = tid & 63;

    __shared__ float xs[T_STEPS];
    __shared__ float red[T_STEPS][2][2];  // [t][wave][o] partial cur2
    __shared__ float redc[2];

    // Stage x row + zero the reduction buffer (120 float4 = 480 floats).
    if (tid < T_STEPS) {
        ((f32x4*)red)[tid] = (f32x4)0.0f;
        xs[tid] = x[(size_t)b * T_STEPS + tid];
    }

    // Per-thread parameters for 4 neurons (vector loads, 16B aligned).
    const f32x4 w1v  = ((const f32x4*)W1)[tid];
    f32x4 bhv        = ((const f32x4*)beta_h)[tid];
    const f32x4 thv  = ((const f32x4*)thr_h)[tid];
    const f32x4 w20v = ((const f32x4*)W2)[tid];          // W2[0][h..h+3]
    const f32x4 w21v = ((const f32x4*)(W2 + HID))[tid];  // W2[1][h..h+3]
    bhv.x = fminf(fmaxf(bhv.x, 0.0f), 1.0f);
    bhv.y = fminf(fmaxf(bhv.y, 0.0f), 1.0f);
    bhv.z = fminf(fmaxf(bhv.z, 0.0f), 1.0f);
    bhv.w = fminf(fmaxf(bhv.w, 0.0f), 1.0f);

    float m0 = 0.0f, m1 = 0.0f, m2 = 0.0f, m3 = 0.0f;
    int hc = 0;  // per-thread hidden spike count

    __syncthreads();  // xs + red ready; the ONLY pre-loop barrier

    const size_t off1    = (size_t)b * HID + (size_t)tid * 4;
    const size_t stride1 = (size_t)BATCH * HID;
    float* sp = spk1_rec + off1;
    float* mp = mem1_rec + off1;

    #pragma unroll 4
    for (int t = 0; t < T_STEPS; ++t) {
        const float xt = xs[t];
        // mem1 = bh*mem1 + xt*w1 — exact op order (no FMA contraction)
        // to match the fp32 reference.
        m0 = __fadd_rn(__fmul_rn(bhv.x, m0), __fmul_rn(xt, w1v.x));
        m1 = __fadd_rn(__fmul_rn(bhv.y, m1), __fmul_rn(xt, w1v.y));
        m2 = __fadd_rn(__fmul_rn(bhv.z, m2), __fmul_rn(xt, w1v.z));
        m3 = __fadd_rn(__fmul_rn(bhv.w, m3), __fmul_rn(xt, w1v.w));

        const bool f0 = m0 > thv.x;
        const bool f1 = m1 > thv.y;
        const bool f2 = m2 > thv.z;
        const bool f3 = m3 > thv.w;
        const float s0 = f0 ? 1.0f : 0.0f;
        const float s1 = f1 ? 1.0f : 0.0f;
        const float s2 = f2 ? 1.0f : 0.0f;
        const float s3 = f3 ? 1.0f : 0.0f;
        m0 = f0 ? 0.0f : m0;
        m1 = f1 ? 0.0f : m1;
        m2 = f2 ? 0.0f : m2;
        m3 = f3 ? 0.0f : m3;
        hc += (int)f0 + (int)f1 + (int)f2 + (int)f3;

        f32x4 sv; sv.x = s0; sv.y = s1; sv.z = s2; sv.w = s3;
        f32x4 mv; mv.x = m0; mv.y = m1; mv.z = m2; mv.w = m3;
        __builtin_nontemporal_store(sv, (f32x4*)sp);
        __builtin_nontemporal_store(mv, (f32x4*)mp);
        sp += stride1;
        mp += stride1;

        // Output-layer partials: only when this wave spiked at all
        // (wave-uniform branch; spikes are rare so common path is free).
        if (__ballot(f0 | f1 | f2 | f3) != 0ULL) {
            float c0 = s0 * w20v.x + s1 * w20v.y + s2 * w20v.z + s3 * w20v.w;
            float c1 = s0 * w21v.x + s1 * w21v.y + s2 * w21v.z + s3 * w21v.w;
            #pragma unroll
            for (int o = 32; o > 0; o >>= 1) {
                c0 += __shfl_down(c0, o, 64);
                c1 += __shfl_down(c1, o, 64);
            }
            if (lane == 0) { red[t][wid][0] = c0; red[t][wid][1] = c1; }
        }
    }

    // Hidden spike count: wave reduce, then cross-wave via LDS.
    float fc = (float)hc;
    #pragma unroll
    for (int o = 32; o > 0; o >>= 1) fc += __shfl_down(fc, o, 64);
    if (lane == 0) redc[wid] = fc;

    __syncthreads();  // red[] + redc[] visible; the ONLY post-loop barrier

    if (tid == 0) atomicAdd(&cnts[0], redc[0] + redc[1]);

    // Output layer: threads 0 and 1 each own one output neuron's serial
    // recurrence over 120 steps (independent chains).
    if (tid < OUTN) {
        const int o = tid;
        const float bo = fminf(fmaxf(beta_o[o], 0.0f), 1.0f);
        const float to = thr_o[o];
        float m = 0.0f;
        int oc = 0;
        const size_t stride2 = (size_t)BATCH * OUTN;
        float* s2p = spk2_rec + (size_t)b * OUTN + o;
        float* m2p = mem2_rec + (size_t)b * OUTN + o;
        #pragma unroll 4
        for (int t = 0; t < T_STEPS; ++t) {
            const float cur = red[t][0][o] + red[t][1][o];
            m = __fadd_rn(__fmul_rn(bo, m), cur);
            const bool f = m > to;
            const float s = f ? 1.0f : 0.0f;
            if (f) { m = 0.0f; oc++; }
            s2p[0] = s;
            m2p[0] = m;
            s2p += stride2;
            m2p += stride2;
        }
        if (oc) atomicAdd(&cnts[1], (float)oc);
    }
}

extern "C" void kernel_launch(void* const* d_in, const int* in_sizes, int n_in,
                              void* d_out, int out_size, void* d_ws, size_t ws_size,
                              hipStream_t stream) {
    const float* x      = (const float*)d_in[0];
    const float* W1     = (const float*)d_in[1];
    const float* W2     = (const float*)d_in[2];
    const float* beta_h = (const float*)d_in[3];
    const float* thr_h  = (const float*)d_in[4];
    const float* beta_o = (const float*)d_in[5];
    const float* thr_o  = (const float*)d_in[6];

    float* out  = (float*)d_out;
    float* spk1 = out + SPK1_OFF;
    float* mem1 = out + MEM1_OFF;
    float* spk2 = out + SPK2_OFF;
    float* mem2 = out + MEM2_OFF;
    float* cnts = out + CNT_OFF;

    // d_out is poisoned 0xAA before timed launches; zero the atomic slots.
    zero_counts_kernel<<<1, 1, 0, stream>>>(cnts);

    snn_fwd_kernel<<<BATCH, 128, 0, stream>>>(
        x, W1, W2, beta_h, thr_h, beta_o, thr_o,
        spk1, mem1, spk2, mem2, cnts);
}

// Round 2
// 1007.706 us; speedup vs baseline: 1.0265x; 1.0265x over previous
//
#include <hip/hip_runtime.h>

// Problem constants (from reference setup_inputs)
#define T_STEPS 120
#define BATCH   2048
#define HID     512
#define OUTN    2
#define G_ROWS  8   // batch rows per block, one per wave

// Output layout (flat, return order):
//  spk1_rec (T,B,H)  : 120*2048*512 = 125829120
//  mem1_rec (T,B,H)  : 125829120
//  spk2_rec (T,B,O)  : 491520
//  mem2_rec (T,B,O)  : 491520
//  hidden_spike_count: 1
//  output_spike_count: 1
#define SPK1_OFF 0LL
#define MEM1_OFF 125829120LL
#define SPK2_OFF 251658240LL
#define MEM2_OFF 252149760LL
#define CNT_OFF  252641280LL

typedef float f32x4 __attribute__((ext_vector_type(4)));
typedef float f32x2 __attribute__((ext_vector_type(2)));

__global__ void zero_counts_kernel(float* cnts) {
    cnts[0] = 0.0f;
    cnts[1] = 0.0f;
}

// 512 threads = 8 waves; wave w owns batch row b = blockIdx.x*8 + w
// entirely (512 hidden neurons = 64 lanes x 8 neurons, as two groups of
// 4 consecutive h). Per t-step a block writes 16 KB CONTIGUOUS per
// output array (8 rows x 2 KB) instead of the previous 2 KB island —
// this is the write-granule fix for DRAM efficiency.
//
// No barriers in the t-loop (waves are fully independent: the output
// layer reduction is wave-local via shuffles; red[] partials are
// wave-private LDS).
//
// Per-component step: exact op order (no FMA contraction) to match the
// fp32 reference bit-for-bit.
#define HSTEP(mm, bb, ww, tt, ss, ff)                                  \
    mm = __fadd_rn(__fmul_rn(bb, mm), __fmul_rn(xt, ww));              \
    const bool  ff = mm > tt;                                          \
    const float ss = ff ? 1.0f : 0.0f;                                 \
    mm = ff ? 0.0f : mm;                                               \
    hc += (int)ff;

__global__ __launch_bounds__(512) void snn_fwd_kernel(
    const float* __restrict__ x,       // (B,T)
    const float* __restrict__ W1,      // (H,1)
    const float* __restrict__ W2,      // (O,H), already *H per setup
    const float* __restrict__ beta_h,  // (H)
    const float* __restrict__ thr_h,   // (H)
    const float* __restrict__ beta_o,  // (O)
    const float* __restrict__ thr_o,   // (O)
    float* __restrict__ spk1_rec,
    float* __restrict__ mem1_rec,
    float* __restrict__ spk2_rec,
    float* __restrict__ mem2_rec,
    float* __restrict__ cnts)
{
    const int tid  = threadIdx.x;
    const int w    = tid >> 6;
    const int lane = tid & 63;
    const int b    = blockIdx.x * G_ROWS + w;

    __shared__ float xs[G_ROWS][T_STEPS];
    __shared__ float red[G_ROWS][T_STEPS][2];  // wave-private cur2 partials

    // Stage this wave's x row + zero its red slice (both wave-private;
    // the single pre-loop barrier makes them visible).
    if (lane < 60) {
        ((f32x2*)xs[w])[lane]  = ((const f32x2*)x)[(size_t)b * (T_STEPS / 2) + lane];
        ((f32x4*)red[w])[lane] = (f32x4)0.0f;  // 60*4 = 240 = 120*2 floats
    }

    // Per-lane parameters: group A = h in [lane*4, lane*4+4),
    // group B = h in [256 + lane*4, 256 + lane*4 + 4).
    const int pA = lane;
    const int pB = 64 + lane;
    const f32x4 w1A  = ((const f32x4*)W1)[pA];
    const f32x4 w1B  = ((const f32x4*)W1)[pB];
    f32x4 bhA        = ((const f32x4*)beta_h)[pA];
    f32x4 bhB        = ((const f32x4*)beta_h)[pB];
    const f32x4 thA  = ((const f32x4*)thr_h)[pA];
    const f32x4 thB  = ((const f32x4*)thr_h)[pB];
    const f32x4 w20A = ((const f32x4*)W2)[pA];           // W2[0][...]
    const f32x4 w20B = ((const f32x4*)W2)[pB];
    const f32x4 w21A = ((const f32x4*)(W2 + HID))[pA];   // W2[1][...]
    const f32x4 w21B = ((const f32x4*)(W2 + HID))[pB];
    bhA.x = fminf(fmaxf(bhA.x, 0.0f), 1.0f);
    bhA.y = fminf(fmaxf(bhA.y, 0.0f), 1.0f);
    bhA.z = fminf(fmaxf(bhA.z, 0.0f), 1.0f);
    bhA.w = fminf(fmaxf(bhA.w, 0.0f), 1.0f);
    bhB.x = fminf(fmaxf(bhB.x, 0.0f), 1.0f);
    bhB.y = fminf(fmaxf(bhB.y, 0.0f), 1.0f);
    bhB.z = fminf(fmaxf(bhB.z, 0.0f), 1.0f);
    bhB.w = fminf(fmaxf(bhB.w, 0.0f), 1.0f);

    float mA0 = 0.f, mA1 = 0.f, mA2 = 0.f, mA3 = 0.f;
    float mB0 = 0.f, mB1 = 0.f, mB2 = 0.f, mB3 = 0.f;
    int hc = 0;

    __syncthreads();  // xs/red ready; the ONLY barrier

    // Store bases: slice index = b*512 + h; group A at lane*4, B at +256.
    const size_t st1 = (size_t)BATCH * HID;
    float* sp = spk1_rec + (size_t)b * HID + (size_t)lane * 4;
    float* mp = mem1_rec + (size_t)b * HID + (size_t)lane * 4;

    #pragma unroll 2
    for (int t = 0; t < T_STEPS; ++t) {
        const float xt = xs[w][t];

        HSTEP(mA0, bhA.x, w1A.x, thA.x, sA0, fA0)
        HSTEP(mA1, bhA.y, w1A.y, thA.y, sA1, fA1)
        HSTEP(mA2, bhA.z, w1A.z, thA.z, sA2, fA2)
        HSTEP(mA3, bhA.w, w1A.w, thA.w, sA3, fA3)
        HSTEP(mB0, bhB.x, w1B.x, thB.x, sB0, fB0)
        HSTEP(mB1, bhB.y, w1B.y, thB.y, sB1, fB1)
        HSTEP(mB2, bhB.z, w1B.z, thB.z, sB2, fB2)
        HSTEP(mB3, bhB.w, w1B.w, thB.w, sB3, fB3)

        f32x4 sAv; sAv.x = sA0; sAv.y = sA1; sAv.z = sA2; sAv.w = sA3;
        f32x4 sBv; sBv.x = sB0; sBv.y = sB1; sBv.z = sB2; sBv.w = sB3;
        f32x4 mAv; mAv.x = mA0; mAv.y = mA1; mAv.z = mA2; mAv.w = mA3;
        f32x4 mBv; mBv.x = mB0; mBv.y = mB1; mBv.z = mB2; mBv.w = mB3;
        __builtin_nontemporal_store(sAv, (f32x4*)sp);
        __builtin_nontemporal_store(sBv, (f32x4*)(sp + 256));
        __builtin_nontemporal_store(mAv, (f32x4*)mp);
        __builtin_nontemporal_store(mBv, (f32x4*)(mp + 256));
        sp += st1;
        mp += st1;

        // Output-layer partials: spikes are ~never, so the wave-uniform
        // ballot guard keeps the common path free.
        if (__ballot(fA0 | fA1 | fA2 | fA3 | fB0 | fB1 | fB2 | fB3) != 0ULL) {
            float c0 = sA0 * w20A.x + sA1 * w20A.y + sA2 * w20A.z + sA3 * w20A.w
                     + sB0 * w20B.x + sB1 * w20B.y + sB2 * w20B.z + sB3 * w20B.w;
            float c1 = sA0 * w21A.x + sA1 * w21A.y + sA2 * w21A.z + sA3 * w21A.w
                     + sB0 * w21B.x + sB1 * w21B.y + sB2 * w21B.z + sB3 * w21B.w;
            #pragma unroll
            for (int o = 32; o > 0; o >>= 1) {
                c0 += __shfl_down(c0, o, 64);
                c1 += __shfl_down(c1, o, 64);
            }
            if (lane == 0) { red[w][t][0] = c0; red[w][t][1] = c1; }
        }
    }

    // Hidden spike count: wave-reduce, lane 0 atomics (8 per block).
    float fc = (float)hc;
    #pragma unroll
    for (int o = 32; o > 0; o >>= 1) fc += __shfl_down(fc, o, 64);
    if (lane == 0) atomicAdd(&cnts[0], fc);

    // Output layer: lanes 0,1 of each wave run their output neuron's
    // serial recurrence for this wave's row (red[] is wave-private; the
    // wave's own in-order LDS ops + compiler lgkmcnt make it visible).
    if (lane < OUTN) {
        const int o = lane;
        const float bo = fminf(fmaxf(beta_o[o], 0.0f), 1.0f);
        const float to = thr_o[o];
        float m = 0.0f;
        int oc = 0;
        const size_t st2 = (size_t)BATCH * OUTN;
        float* s2p = spk2_rec + (size_t)b * OUTN + o;
        float* m2p = mem2_rec + (size_t)b * OUTN + o;
        #pragma unroll 4
        for (int t = 0; t < T_STEPS; ++t) {
            const float cur = red[w][t][o];
            m = __fadd_rn(__fmul_rn(bo, m), cur);
            const bool f = m > to;
            s2p[0] = f ? 1.0f : 0.0f;
            if (f) { m = 0.0f; oc++; }
            m2p[0] = m;
            s2p += st2;
            m2p += st2;
        }
        if (oc) atomicAdd(&cnts[1], (float)oc);
    }
}

extern "C" void kernel_launch(void* const* d_in, const int* in_sizes, int n_in,
                              void* d_out, int out_size, void* d_ws, size_t ws_size,
                              hipStream_t stream) {
    const float* x      = (const float*)d_in[0];
    const float* W1     = (const float*)d_in[1];
    const float* W2     = (const float*)d_in[2];
    const float* beta_h = (const float*)d_in[3];
    const float* thr_h  = (const float*)d_in[4];
    const float* beta_o = (const float*)d_in[5];
    const float* thr_o  = (const float*)d_in[6];

    float* out  = (float*)d_out;
    float* spk1 = out + SPK1_OFF;
    float* mem1 = out + MEM1_OFF;
    float* spk2 = out + SPK2_OFF;
    float* mem2 = out + MEM2_OFF;
    float* cnts = out + CNT_OFF;

    // d_out is poisoned 0xAA before timed launches; zero the atomic slots.
    zero_counts_kernel<<<1, 1, 0, stream>>>(cnts);

    snn_fwd_kernel<<<BATCH / G_ROWS, 512, 0, stream>>>(
        x, W1, W2, beta_h, thr_h, beta_o, thr_o,
        spk1, mem1, spk2, mem2, cnts);
}

// Round 3
// 1001.948 us; speedup vs baseline: 1.0324x; 1.0057x over previous
//
#include <hip/hip_runtime.h>

// Problem constants (from reference setup_inputs)
#define T_STEPS 120
#define BATCH   2048
#define HID     512
#define OUTN    2
#define G_ROWS  8               // batch rows per block, one per wave
#define NBLK    (BATCH / G_ROWS) // 256 blocks

// Output layout (flat, return order):
//  spk1_rec (T,B,H)  : 120*2048*512 = 125829120
//  mem1_rec (T,B,H)  : 125829120
//  spk2_rec (T,B,O)  : 491520
//  mem2_rec (T,B,O)  : 491520
//  hidden_spike_count: 1
//  output_spike_count: 1
#define SPK1_OFF 0LL
#define MEM1_OFF 125829120LL
#define SPK2_OFF 251658240LL
#define MEM2_OFF 252149760LL
#define CNT_OFF  252641280LL

typedef float f32x4 __attribute__((ext_vector_type(4)));
typedef float f32x2 __attribute__((ext_vector_type(2)));

// Sums the per-block count partials from workspace and writes the two
// scalar outputs with plain stores (single writer — no atomics anywhere).
__global__ __launch_bounds__(256) void count_reduce_kernel(
    const float* __restrict__ ws, float* __restrict__ cnts)
{
    const int tid  = threadIdx.x;
    const int w    = tid >> 6;
    const int lane = tid & 63;
    float h = ws[tid];          // hidden partials [0,256)
    float o = ws[NBLK + tid];   // output partials [256,512)
    #pragma unroll
    for (int off = 32; off > 0; off >>= 1) {
        h += __shfl_down(h, off, 64);
        o += __shfl_down(o, off, 64);
    }
    __shared__ float sh[4][2];
    if (lane == 0) { sh[w][0] = h; sh[w][1] = o; }
    __syncthreads();
    if (tid == 0) {
        cnts[0] = sh[0][0] + sh[1][0] + sh[2][0] + sh[3][0];
        cnts[1] = sh[0][1] + sh[1][1] + sh[2][1] + sh[3][1];
    }
}

// 512 threads = 8 waves; wave w owns batch row b = blockIdx.x*8 + w
// entirely (512 hidden neurons = 64 lanes x two groups of 4 consecutive
// h). Main t-loop identical to the previous round (no barriers, f32x4
// nontemporal stores, 16 KB contiguous per block per t-slice).
//
// Changes this round (serialization-tail theory):
//  * No atomics: per-block count partials go to d_ws, reduced by
//    count_reduce_kernel.
//  * spk2/mem2 staged in LDS tiles and written as full 64B lines by a
//    cooperative copy (previously 8B masked writes per wave per t).
#define HSTEP(mm, bb, ww, tt, ss, ff)                                  \
    mm = __fadd_rn(__fmul_rn(bb, mm), __fmul_rn(xt, ww));              \
    const bool  ff = mm > tt;                                          \
    const float ss = ff ? 1.0f : 0.0f;                                 \
    mm = ff ? 0.0f : mm;                                               \
    hc += (int)ff;

__global__ __launch_bounds__(512) void snn_fwd_kernel(
    const float* __restrict__ x,       // (B,T)
    const float* __restrict__ W1,      // (H,1)
    const float* __restrict__ W2,      // (O,H), already *H per setup
    const float* __restrict__ beta_h,  // (H)
    const float* __restrict__ thr_h,   // (H)
    const float* __restrict__ beta_o,  // (O)
    const float* __restrict__ thr_o,   // (O)
    float* __restrict__ spk1_rec,
    float* __restrict__ mem1_rec,
    float* __restrict__ spk2_rec,
    float* __restrict__ mem2_rec,
    float* __restrict__ ws)            // d_ws: [0,256) hid, [256,512) out
{
    const int tid  = threadIdx.x;
    const int w    = tid >> 6;
    const int lane = tid & 63;
    const int b    = blockIdx.x * G_ROWS + w;

    __shared__ float xs[G_ROWS][T_STEPS];
    __shared__ float red[G_ROWS][T_STEPS][2];   // wave-private cur2 partials
    __shared__ float s2tile[T_STEPS][G_ROWS * OUTN];  // spk2 staging
    __shared__ float m2tile[T_STEPS][G_ROWS * OUTN];  // mem2 staging
    __shared__ float redc[G_ROWS];
    __shared__ float redo[G_ROWS];

    // Stage this wave's x row + zero its red slice (both wave-private).
    if (lane < 60) {
        ((f32x2*)xs[w])[lane]  = ((const f32x2*)x)[(size_t)b * (T_STEPS / 2) + lane];
        ((f32x4*)red[w])[lane] = (f32x4)0.0f;  // 60*4 = 240 = 120*2 floats
    }

    // Per-lane parameters: group A = h in [lane*4, lane*4+4),
    // group B = h in [256 + lane*4, 256 + lane*4 + 4).
    const int pA = lane;
    const int pB = 64 + lane;
    const f32x4 w1A  = ((const f32x4*)W1)[pA];
    const f32x4 w1B  = ((const f32x4*)W1)[pB];
    f32x4 bhA        = ((const f32x4*)beta_h)[pA];
    f32x4 bhB        = ((const f32x4*)beta_h)[pB];
    const f32x4 thA  = ((const f32x4*)thr_h)[pA];
    const f32x4 thB  = ((const f32x4*)thr_h)[pB];
    const f32x4 w20A = ((const f32x4*)W2)[pA];           // W2[0][...]
    const f32x4 w20B = ((const f32x4*)W2)[pB];
    const f32x4 w21A = ((const f32x4*)(W2 + HID))[pA];   // W2[1][...]
    const f32x4 w21B = ((const f32x4*)(W2 + HID))[pB];
    bhA.x = fminf(fmaxf(bhA.x, 0.0f), 1.0f);
    bhA.y = fminf(fmaxf(bhA.y, 0.0f), 1.0f);
    bhA.z = fminf(fmaxf(bhA.z, 0.0f), 1.0f);
    bhA.w = fminf(fmaxf(bhA.w, 0.0f), 1.0f);
    bhB.x = fminf(fmaxf(bhB.x, 0.0f), 1.0f);
    bhB.y = fminf(fmaxf(bhB.y, 0.0f), 1.0f);
    bhB.z = fminf(fmaxf(bhB.z, 0.0f), 1.0f);
    bhB.w = fminf(fmaxf(bhB.w, 0.0f), 1.0f);

    float mA0 = 0.f, mA1 = 0.f, mA2 = 0.f, mA3 = 0.f;
    float mB0 = 0.f, mB1 = 0.f, mB2 = 0.f, mB3 = 0.f;
    int hc = 0;

    __syncthreads();  // xs/red ready

    // Store bases: slice index = b*512 + h; group A at lane*4, B at +256.
    const size_t st1 = (size_t)BATCH * HID;
    float* sp = spk1_rec + (size_t)b * HID + (size_t)lane * 4;
    float* mp = mem1_rec + (size_t)b * HID + (size_t)lane * 4;

    #pragma unroll 2
    for (int t = 0; t < T_STEPS; ++t) {
        const float xt = xs[w][t];

        HSTEP(mA0, bhA.x, w1A.x, thA.x, sA0, fA0)
        HSTEP(mA1, bhA.y, w1A.y, thA.y, sA1, fA1)
        HSTEP(mA2, bhA.z, w1A.z, thA.z, sA2, fA2)
        HSTEP(mA3, bhA.w, w1A.w, thA.w, sA3, fA3)
        HSTEP(mB0, bhB.x, w1B.x, thB.x, sB0, fB0)
        HSTEP(mB1, bhB.y, w1B.y, thB.y, sB1, fB1)
        HSTEP(mB2, bhB.z, w1B.z, thB.z, sB2, fB2)
        HSTEP(mB3, bhB.w, w1B.w, thB.w, sB3, fB3)

        f32x4 sAv; sAv.x = sA0; sAv.y = sA1; sAv.z = sA2; sAv.w = sA3;
        f32x4 sBv; sBv.x = sB0; sBv.y = sB1; sBv.z = sB2; sBv.w = sB3;
        f32x4 mAv; mAv.x = mA0; mAv.y = mA1; mAv.z = mA2; mAv.w = mA3;
        f32x4 mBv; mBv.x = mB0; mBv.y = mB1; mBv.z = mB2; mBv.w = mB3;
        __builtin_nontemporal_store(sAv, (f32x4*)sp);
        __builtin_nontemporal_store(sBv, (f32x4*)(sp + 256));
        __builtin_nontemporal_store(mAv, (f32x4*)mp);
        __builtin_nontemporal_store(mBv, (f32x4*)(mp + 256));
        sp += st1;
        mp += st1;

        // Output-layer partials: spikes are ~never, so the wave-uniform
        // ballot guard keeps the common path free.
        if (__ballot(fA0 | fA1 | fA2 | fA3 | fB0 | fB1 | fB2 | fB3) != 0ULL) {
            float c0 = sA0 * w20A.x + sA1 * w20A.y + sA2 * w20A.z + sA3 * w20A.w
                     + sB0 * w20B.x + sB1 * w20B.y + sB2 * w20B.z + sB3 * w20B.w;
            float c1 = sA0 * w21A.x + sA1 * w21A.y + sA2 * w21A.z + sA3 * w21A.w
                     + sB0 * w21B.x + sB1 * w21B.y + sB2 * w21B.z + sB3 * w21B.w;
            #pragma unroll
            for (int o = 32; o > 0; o >>= 1) {
                c0 += __shfl_down(c0, o, 64);
                c1 += __shfl_down(c1, o, 64);
            }
            if (lane == 0) { red[w][t][0] = c0; red[w][t][1] = c1; }
        }
    }

    // Hidden spike count: wave-reduce into redc[w] (no atomics).
    float fc = (float)hc;
    #pragma unroll
    for (int o = 32; o > 0; o >>= 1) fc += __shfl_down(fc, o, 64);
    if (lane == 0) redc[w] = fc;

    // Output layer: lanes 0,1 of each wave run their output neuron's
    // serial recurrence for this wave's row, staging results into the
    // LDS tiles (red[w] is wave-private; in-order LDS ops make it
    // visible to the same wave without a barrier).
    float ocf = 0.0f;
    if (lane < OUTN) {
        const int o = lane;
        const float bo = fminf(fmaxf(beta_o[o], 0.0f), 1.0f);
        const float to = thr_o[o];
        float m = 0.0f;
        #pragma unroll 4
        for (int t = 0; t < T_STEPS; ++t) {
            const float cur = red[w][t][o];
            m = __fadd_rn(__fmul_rn(bo, m), cur);
            const bool f = m > to;
            if (f) { m = 0.0f; ocf += 1.0f; }
            s2tile[t][w * OUTN + o] = f ? 1.0f : 0.0f;
            m2tile[t][w * OUTN + o] = m;
        }
    }
    // lane0 += lane1's output count, stash per-wave.
    ocf += __shfl_down(ocf, 1, 64);
    if (lane == 0) redo[w] = ocf;

    __syncthreads();  // tiles + redc/redo visible

    if (tid == 0) {
        float th_ = 0.f, to_ = 0.f;
        #pragma unroll
        for (int i = 0; i < G_ROWS; ++i) { th_ += redc[i]; to_ += redo[i]; }
        ws[blockIdx.x]        = th_;
        ws[NBLK + blockIdx.x] = to_;
    }

    // Cooperative tile flush: each t-slice chunk is one full 64B line
    // (16 floats, rows b0..b0+7 x o0..o1) with a single writer.
    const size_t base2 = (size_t)blockIdx.x * G_ROWS * OUTN;
    const float* s2t = &s2tile[0][0];
    const float* m2t = &m2tile[0][0];
    #pragma unroll
    for (int e = tid; e < T_STEPS * G_ROWS * OUTN; e += 512) {
        const int t = e >> 4;
        const int c = e & 15;
        const size_t g = (size_t)t * (BATCH * OUTN) + base2 + c;
        spk2_rec[g] = s2t[e];
        mem2_rec[g] = m2t[e];
    }
}

extern "C" void kernel_launch(void* const* d_in, const int* in_sizes, int n_in,
                              void* d_out, int out_size, void* d_ws, size_t ws_size,
                              hipStream_t stream) {
    const float* x      = (const float*)d_in[0];
    const float* W1     = (const float*)d_in[1];
    const float* W2     = (const float*)d_in[2];
    const float* beta_h = (const float*)d_in[3];
    const float* thr_h  = (const float*)d_in[4];
    const float* beta_o = (const float*)d_in[5];
    const float* thr_o  = (const float*)d_in[6];

    float* out  = (float*)d_out;
    float* spk1 = out + SPK1_OFF;
    float* mem1 = out + MEM1_OFF;
    float* spk2 = out + SPK2_OFF;
    float* mem2 = out + MEM2_OFF;
    float* cnts = out + CNT_OFF;
    float* wsf  = (float*)d_ws;   // 512 floats of workspace

    snn_fwd_kernel<<<NBLK, 512, 0, stream>>>(
        x, W1, W2, beta_h, thr_h, beta_o, thr_o,
        spk1, mem1, spk2, mem2, wsf);

    count_reduce_kernel<<<1, 256, 0, stream>>>(wsf, cnts);
}